// Round 5
// baseline (71.668 us; speedup 1.0000x reference)
//
#include <hip/hip_runtime.h>

// NT-Xent loss, fused: never materialize the 8192x8192 similarity matrix.
// z = concat(z1,z2) [8192,256] f32 -> normalize -> bf16 zn (ws)
// S = zn @ zn^T via mfma_f32_16x16x32_bf16, fused per-row sum of exp(2*cos - 2)
// (fixed logsumexp max = 2: logits bounded by |cos|/T <= 2 -> partials additive)
// nll_r = -pos_r + 2 + log(sum_r); out = mean(nll)
//
// R5: T3+T4+T5 pipeline on the R4 structure. 3-buffer LDS (48KB), 2-phase-deep
// DMA prefetch with counted s_waitcnt vmcnt(4) (never 0 in steady state) + raw
// s_barrier; CSPLIT=32 -> 2048 blocks (8/CU turnover, kills the 4-into-3 tail);
// s_setprio(1) around each tile's MFMA cluster.

#define NHALF 4096
#define N2 8192
#define D 256
#define CSPLIT 32
#define TPC 16      // 16-col tiles per chunk
#define PHASES 8    // 2 tiles per phase
#define RPB 128     // rows per block (4 waves x 32)

typedef __attribute__((ext_vector_type(8))) short short8;
typedef __attribute__((ext_vector_type(4))) float f32x4;
typedef __attribute__((ext_vector_type(4))) unsigned short u16x4;

__device__ __forceinline__ unsigned short f2bf(float f) {
  unsigned int u = __float_as_uint(f);
  unsigned int r = (u + 0x7fffu + ((u >> 16) & 1u)) >> 16;  // RNE
  return (unsigned short)r;
}

__device__ __forceinline__ void gload_lds16(const void* g, void* l) {
  __builtin_amdgcn_global_load_lds(
      (const __attribute__((address_space(1))) unsigned int*)g,
      (__attribute__((address_space(3))) unsigned int*)l, 16, 0, 0);
}

// ---------------- Kernel 1: row-normalize to bf16 ----------------
__global__ __launch_bounds__(256) void norm_kernel(const float* __restrict__ z1,
                                                   const float* __restrict__ z2,
                                                   short* __restrict__ zn) {
  const int lane = threadIdx.x & 63;
  const int row = blockIdx.x * 4 + (threadIdx.x >> 6);
  const float* src = (row < NHALF) ? (z1 + (size_t)row * D)
                                   : (z2 + (size_t)(row - NHALF) * D);
  const float4 v = *(const float4*)(src + lane * 4);
  float ss = v.x * v.x + v.y * v.y + v.z * v.z + v.w * v.w;
  #pragma unroll
  for (int m = 1; m < 64; m <<= 1) ss += __shfl_xor(ss, m);
  const float inv = 1.0f / fmaxf(sqrtf(ss), 1e-8f);
  u16x4 o;
  o[0] = f2bf(v.x * inv);
  o[1] = f2bf(v.y * inv);
  o[2] = f2bf(v.z * inv);
  o[3] = f2bf(v.w * inv);
  *(u16x4*)(zn + (size_t)row * D + lane * 4) = o;
}

// ---------------- Kernel 2: fused Gram + partial exp-sums ----------------
// grid (64 row-blocks, 32 col-chunks), 256 threads = 4 waves.
// Wave owns 32 rows (2 stripes of 16); A-frags in registers; B shared in LDS.
// mfma_f32_16x16x32_bf16: A/B lane l -> row/col (l&15), k = 8*(l>>4)+e
//                         D lane l -> col (l&15), row = 4*(l>>4)+reg
// LDS B: 3 buffers x [2 tiles][16 rows][512 B], byte-swizzle x^=((row&7)<<4)
// applied to BOTH the global source and the ds_read (rule #21).
__global__ __launch_bounds__(256, 3) void simlse_kernel(const short* __restrict__ zn,
                                                        float* __restrict__ sum_ws,
                                                        float* __restrict__ pos_ws) {
  __shared__ __align__(16) char bsm[49152];  // 3 x 16 KB
  const int lane = threadIdx.x & 63;
  const int wave = threadIdx.x >> 6;
  const int rlo = lane & 15;
  const int hi = lane >> 4;
  const int khi = hi * 8;
  const int rowbase = blockIdx.x * RPB + wave * 32;
  const int cc = blockIdx.y;
  const int ct0 = cc * TPC;

  // A fragments: 2 stripes x 8 K-steps, 16B contiguous per lane.
  short8 a[2][8];
  #pragma unroll
  for (int st = 0; st < 2; ++st) {
    const short* p = zn + (size_t)(rowbase + st * 16 + rlo) * D + khi;
    #pragma unroll
    for (int kk = 0; kk < 8; ++kk) a[st][kk] = *(const short8*)(p + kk * 32);
  }
  #pragma unroll
  for (int st = 0; st < 2; ++st)
    #pragma unroll
    for (int kk = 0; kk < 8; ++kk)
      asm volatile("" : "+v"(a[st][kk]));

  float lsum[2][4];
  #pragma unroll
  for (int st = 0; st < 2; ++st)
    #pragma unroll
    for (int g = 0; g < 4; ++g) lsum[st][g] = 0.0f;

  int dt[2], pt[2];
  #pragma unroll
  for (int st = 0; st < 2; ++st) {
    dt[st] = (rowbase + st * 16) >> 4;
    pt[st] = ((rowbase + st * 16 + NHALF) & (N2 - 1)) >> 4;
  }

  const char* znb = (const char*)zn;

  // Stage 2 tiles (16 KB) of B into LDS buffer `buf`.
  // LDS linear byte x in [0,16384): tile j = x>>13, row = (x>>9)&15.
  // LDS[x] = global[tile][ (x&8191) ^ ((row&7)<<4) ]  (XOR involution).
  auto stage = [&](int buf, int ph) {
    const int ctbase = ct0 + ph * 2;
    #pragma unroll
    for (int s = 0; s < 4; ++s) {
      const int y = s * 4096 + wave * 1024 + lane * 16;
      const int off = y & 8191;
      const int srcoff = off ^ (((off >> 9) & 7) << 4);
      const void* gp = znb + (size_t)(ctbase + (y >> 13)) * 8192 + srcoff;
      void* lp = bsm + buf * 16384 + s * 4096 + wave * 1024;  // + lane*16 by HW
      gload_lds16(gp, lp);
    }
  };

  auto compute = [&](int buf, int ph) {
    #pragma unroll
    for (int j = 0; j < 2; ++j) {
      const int ct = ct0 + ph * 2 + j;
      const char* tb = bsm + buf * 16384 + j * 8192;
      f32x4 acc[2];
      acc[0] = (f32x4){0.f, 0.f, 0.f, 0.f};
      acc[1] = (f32x4){0.f, 0.f, 0.f, 0.f};
      __builtin_amdgcn_s_setprio(1);
      #pragma unroll
      for (int kk = 0; kk < 8; ++kk) {
        const int c = (kk * 64 + hi * 16) ^ ((rlo & 7) << 4);  // swizzled read
        const short8 b = *(const short8*)(tb + rlo * 512 + c);
        acc[0] = __builtin_amdgcn_mfma_f32_16x16x32_bf16(a[0][kk], b, acc[0], 0, 0, 0);
        acc[1] = __builtin_amdgcn_mfma_f32_16x16x32_bf16(a[1][kk], b, acc[1], 0, 0, 0);
      }
      __builtin_amdgcn_s_setprio(0);
      #pragma unroll
      for (int st = 0; st < 2; ++st) {
        const bool isd = (ct == dt[st]);
        const bool isp = (ct == pt[st]);
        if (!isd && !isp) {
          #pragma unroll
          for (int g = 0; g < 4; ++g)
            lsum[st][g] += __expf(fmaf(acc[st][g], 2.0f, -2.0f));
        } else {
          #pragma unroll
          for (int g = 0; g < 4; ++g) {
            const int rl = (hi << 2) + g;   // local row 0..15
            const bool hit = (rlo == rl);   // tile-diagonal element
            float e = __expf(fmaf(acc[st][g], 2.0f, -2.0f));
            if (isd && hit) e = 0.0f;       // mask self-similarity
            if (isp && hit) pos_ws[rowbase + st * 16 + rl] = acc[st][g] * 2.0f;
            lsum[st][g] += e;
          }
        }
      }
    }
  };

  // T3+T4: 2-phase-deep DMA pipeline, counted vmcnt, raw barriers.
  // Steady state: buffers hold {ph ready-after-wait, ph+1 in flight, ph+2 in
  // flight-after-stage}; own outstanding DMA ops <= 8; vmcnt(4) retires ph's 4.
  stage(0, 0);
  stage(1, 1);
  for (int ph = 0; ph < PHASES; ++ph) {
    if (ph + 1 < PHASES) {
      asm volatile("s_waitcnt vmcnt(4)" ::: "memory");
    } else {
      asm volatile("s_waitcnt vmcnt(0)" ::: "memory");
    }
    __builtin_amdgcn_s_barrier();       // everyone's DMA(ph) done; buf[(ph+2)%3]
    __builtin_amdgcn_sched_barrier(0);  // no longer read by anyone
    if (ph + 2 < PHASES) stage((ph + 2) % 3, ph + 2);
    compute(ph % 3, ph);
  }

  // Reduce exp-sums across the 16-lane column group.
  #pragma unroll
  for (int st = 0; st < 2; ++st)
    #pragma unroll
    for (int g = 0; g < 4; ++g) {
      #pragma unroll
      for (int m = 1; m < 16; m <<= 1)
        lsum[st][g] += __shfl_xor(lsum[st][g], m);
    }

  if (rlo == 0) {
    #pragma unroll
    for (int st = 0; st < 2; ++st)
      #pragma unroll
      for (int g = 0; g < 4; ++g) {
        const int r = rowbase + st * 16 + (hi << 2) + g;
        sum_ws[(size_t)r * CSPLIT + cc] = lsum[st][g];
      }
  }
}

// ---------------- Kernel 3a: per-row nll + per-block partial sum ----------------
__global__ __launch_bounds__(256) void nll_kernel(const float* __restrict__ sum_ws,
                                                  const float* __restrict__ pos_ws,
                                                  float* __restrict__ partial) {
  const int r = blockIdx.x * 256 + threadIdx.x;
  const float4* sp = (const float4*)(sum_ws + (size_t)r * CSPLIT);
  float t = 0.0f;
  #pragma unroll
  for (int i = 0; i < CSPLIT / 4; ++i) {
    const float4 v = sp[i];
    t += v.x + v.y + v.z + v.w;
  }
  float nll = -pos_ws[r] + 2.0f + __logf(t);
  #pragma unroll
  for (int m = 1; m < 64; m <<= 1) nll += __shfl_xor(nll, m);
  __shared__ float red[4];
  const int lane = threadIdx.x & 63;
  const int wave = threadIdx.x >> 6;
  if (lane == 0) red[wave] = nll;
  __syncthreads();
  if (threadIdx.x == 0) partial[blockIdx.x] = red[0] + red[1] + red[2] + red[3];
}

// ---------------- Kernel 3b: final mean ----------------
__global__ __launch_bounds__(64) void final_kernel(const float* __restrict__ partial,
                                                   float* __restrict__ out) {
  const int lane = threadIdx.x;
  float v = (lane < 32) ? partial[lane] : 0.0f;
  #pragma unroll
  for (int m = 1; m < 64; m <<= 1) v += __shfl_xor(v, m);
  if (lane == 0) out[0] = v * (1.0f / (float)N2);
}

extern "C" void kernel_launch(void* const* d_in, const int* in_sizes, int n_in,
                              void* d_out, int out_size, void* d_ws, size_t ws_size,
                              hipStream_t stream) {
  const float* z1 = (const float*)d_in[0];
  const float* z2 = (const float*)d_in[1];
  float* out = (float*)d_out;

  char* ws = (char*)d_ws;
  short* zn = (short*)ws;                                   // 8192*256*2 = 4 MB
  float* sum_ws = (float*)(ws + (size_t)N2 * D * 2);        // 8192*32*4 = 1 MB
  float* pos_ws = sum_ws + (size_t)N2 * CSPLIT;             // 8192*4 = 32 KB
  float* partial = pos_ws + N2;                             // 32 floats

  hipLaunchKernelGGL(norm_kernel, dim3(N2 / 4), dim3(256), 0, stream, z1, z2, zn);
  hipLaunchKernelGGL(simlse_kernel, dim3(N2 / RPB, CSPLIT), dim3(256), 0, stream,
                     zn, sum_ws, pos_ws);
  hipLaunchKernelGGL(nll_kernel, dim3(N2 / 256), dim3(256), 0, stream, sum_ws, pos_ws, partial);
  hipLaunchKernelGGL(final_kernel, dim3(1), dim3(64), 0, stream, partial, out);
}

// Round 6
// 53.601 us; speedup vs baseline: 1.3371x; 1.3371x over previous
//
#include <hip/hip_runtime.h>

// NT-Xent loss, fused: never materialize the 8192x8192 similarity matrix.
// z = concat(z1,z2) [8192,256] f32 -> normalize -> bf16 zn (ws)
// S = zn @ zn^T via mfma_f32_16x16x32_bf16, fused per-row sum of exp(2*cos - 2)
// (fixed logsumexp max = 2: logits bounded by |cos|/T <= 2 -> partials additive)
// nll_r = -pos_r + 2 + log(sum_r); out = mean(nll)
//
// R6: revert to R4 structure (R5's counted-vmcnt 3-buffer graft caused scratch
// spill/fill: WRITE_SIZE 0.5->90 MB, regression). Single change vs R4:
// __launch_bounds__(256,4) -> exactly 4 blocks/CU resident, no 256-block tail,
// 16 waves/CU to overlap the per-phase barrier drain.

#define NHALF 4096
#define N2 8192
#define D 256
#define CSPLIT 16
#define TPC 32      // 16-col tiles per chunk
#define PHASES 16   // 2 tiles per phase
#define RPB 128     // rows per block (4 waves x 32)

typedef __attribute__((ext_vector_type(8))) short short8;
typedef __attribute__((ext_vector_type(4))) float f32x4;
typedef __attribute__((ext_vector_type(4))) unsigned short u16x4;

__device__ __forceinline__ unsigned short f2bf(float f) {
  unsigned int u = __float_as_uint(f);
  unsigned int r = (u + 0x7fffu + ((u >> 16) & 1u)) >> 16;  // RNE
  return (unsigned short)r;
}

__device__ __forceinline__ void gload_lds16(const void* g, void* l) {
  __builtin_amdgcn_global_load_lds(
      (const __attribute__((address_space(1))) unsigned int*)g,
      (__attribute__((address_space(3))) unsigned int*)l, 16, 0, 0);
}

// ---------------- Kernel 1: row-normalize to bf16 ----------------
__global__ __launch_bounds__(256) void norm_kernel(const float* __restrict__ z1,
                                                   const float* __restrict__ z2,
                                                   short* __restrict__ zn) {
  const int lane = threadIdx.x & 63;
  const int row = blockIdx.x * 4 + (threadIdx.x >> 6);
  const float* src = (row < NHALF) ? (z1 + (size_t)row * D)
                                   : (z2 + (size_t)(row - NHALF) * D);
  const float4 v = *(const float4*)(src + lane * 4);
  float ss = v.x * v.x + v.y * v.y + v.z * v.z + v.w * v.w;
  #pragma unroll
  for (int m = 1; m < 64; m <<= 1) ss += __shfl_xor(ss, m);
  const float inv = 1.0f / fmaxf(sqrtf(ss), 1e-8f);
  u16x4 o;
  o[0] = f2bf(v.x * inv);
  o[1] = f2bf(v.y * inv);
  o[2] = f2bf(v.z * inv);
  o[3] = f2bf(v.w * inv);
  *(u16x4*)(zn + (size_t)row * D + lane * 4) = o;
}

// ---------------- Kernel 2: fused Gram + partial exp-sums ----------------
// grid (64 row-blocks, 16 col-chunks), 256 threads = 4 waves.
// Wave owns 32 rows (2 stripes of 16); A-frags in registers; B shared in LDS.
// mfma_f32_16x16x32_bf16: A/B lane l -> row/col (l&15), k = 8*(l>>4)+e
//                         D lane l -> col (l&15), row = 4*(l>>4)+reg
// LDS B layout: [2 halves][2 tiles][16 rows][512 B], byte-swizzled
// x -> x ^ ((row&7)<<4) applied on BOTH the global source and the ds_read.
__global__ __launch_bounds__(256, 4) void simlse_kernel(const short* __restrict__ zn,
                                                        float* __restrict__ sum_ws,
                                                        float* __restrict__ pos_ws) {
  __shared__ __align__(16) char bsm[32768];
  const int lane = threadIdx.x & 63;
  const int wave = threadIdx.x >> 6;
  const int rlo = lane & 15;
  const int hi = lane >> 4;
  const int khi = hi * 8;
  const int rowbase = blockIdx.x * RPB + wave * 32;
  const int cc = blockIdx.y;
  const int ct0 = cc * TPC;

  // A fragments: 2 stripes x 8 K-steps, 16B contiguous per lane.
  short8 a[2][8];
  #pragma unroll
  for (int st = 0; st < 2; ++st) {
    const short* p = zn + (size_t)(rowbase + st * 16 + rlo) * D + khi;
    #pragma unroll
    for (int kk = 0; kk < 8; ++kk) a[st][kk] = *(const short8*)(p + kk * 32);
  }
  #pragma unroll
  for (int st = 0; st < 2; ++st)
    #pragma unroll
    for (int kk = 0; kk < 8; ++kk)
      asm volatile("" : "+v"(a[st][kk]));

  float lsum[2][4];
  #pragma unroll
  for (int st = 0; st < 2; ++st)
    #pragma unroll
    for (int g = 0; g < 4; ++g) lsum[st][g] = 0.0f;

  int dt[2], pt[2];
  #pragma unroll
  for (int st = 0; st < 2; ++st) {
    dt[st] = (rowbase + st * 16) >> 4;
    pt[st] = ((rowbase + st * 16 + NHALF) & (N2 - 1)) >> 4;
  }

  const char* znb = (const char*)zn;

  // Stage 2 tiles (16 KB) of B into LDS half `half` via global_load_lds.
  // LDS linear byte x in [0,16384): tile j = x>>13, row = (x>>9)&15.
  // LDS[x] = global[tile][ (x&8191) ^ ((row&7)<<4) ]  (XOR is an involution).
  auto stage = [&](int half, int ph) {
    const int ctbase = ct0 + ph * 2;
    #pragma unroll
    for (int s = 0; s < 4; ++s) {
      const int y = s * 4096 + wave * 1024 + lane * 16;
      const int off = y & 8191;
      const int srcoff = off ^ (((off >> 9) & 7) << 4);
      const void* gp = znb + (size_t)(ctbase + (y >> 13)) * 8192 + srcoff;
      void* lp = bsm + half * 16384 + s * 4096 + wave * 1024;  // + lane*16 by HW
      gload_lds16(gp, lp);
    }
  };

  auto compute = [&](int half, int ph) {
    #pragma unroll
    for (int j = 0; j < 2; ++j) {
      const int ct = ct0 + ph * 2 + j;
      const char* tb = bsm + half * 16384 + j * 8192;
      f32x4 acc[2];
      acc[0] = (f32x4){0.f, 0.f, 0.f, 0.f};
      acc[1] = (f32x4){0.f, 0.f, 0.f, 0.f};
      #pragma unroll
      for (int kk = 0; kk < 8; ++kk) {
        const int c = (kk * 64 + hi * 16) ^ ((rlo & 7) << 4);  // swizzled read
        const short8 b = *(const short8*)(tb + rlo * 512 + c);
        acc[0] = __builtin_amdgcn_mfma_f32_16x16x32_bf16(a[0][kk], b, acc[0], 0, 0, 0);
        acc[1] = __builtin_amdgcn_mfma_f32_16x16x32_bf16(a[1][kk], b, acc[1], 0, 0, 0);
      }
      #pragma unroll
      for (int st = 0; st < 2; ++st) {
        const bool isd = (ct == dt[st]);
        const bool isp = (ct == pt[st]);
        if (!isd && !isp) {
          #pragma unroll
          for (int g = 0; g < 4; ++g)
            lsum[st][g] += __expf(fmaf(acc[st][g], 2.0f, -2.0f));
        } else {
          #pragma unroll
          for (int g = 0; g < 4; ++g) {
            const int rl = (hi << 2) + g;   // local row 0..15
            const bool hit = (rlo == rl);   // tile-diagonal element
            float e = __expf(fmaf(acc[st][g], 2.0f, -2.0f));
            if (isd && hit) e = 0.0f;       // mask self-similarity
            if (isp && hit) pos_ws[rowbase + st * 16 + rl] = acc[st][g] * 2.0f;
            lsum[st][g] += e;
          }
        }
      }
    }
  };

  stage(0, 0);
  __syncthreads();
  for (int ph = 0; ph < PHASES; ++ph) {
    if (ph + 1 < PHASES) stage((ph + 1) & 1, ph + 1);  // DMA overlaps compute
    compute(ph & 1, ph);
    __syncthreads();  // drains DMA (vmcnt) + ds_reads before buffer swap
  }

  // Reduce exp-sums across the 16-lane column group.
  #pragma unroll
  for (int st = 0; st < 2; ++st)
    #pragma unroll
    for (int g = 0; g < 4; ++g) {
      #pragma unroll
      for (int m = 1; m < 16; m <<= 1)
        lsum[st][g] += __shfl_xor(lsum[st][g], m);
    }

  if (rlo == 0) {
    #pragma unroll
    for (int st = 0; st < 2; ++st)
      #pragma unroll
      for (int g = 0; g < 4; ++g) {
        const int r = rowbase + st * 16 + (hi << 2) + g;
        sum_ws[(size_t)r * CSPLIT + cc] = lsum[st][g];
      }
  }
}

// ---------------- Kernel 3a: per-row nll + per-block partial sum ----------------
__global__ __launch_bounds__(256) void nll_kernel(const float* __restrict__ sum_ws,
                                                  const float* __restrict__ pos_ws,
                                                  float* __restrict__ partial) {
  const int r = blockIdx.x * 256 + threadIdx.x;
  const float4* sp = (const float4*)(sum_ws + (size_t)r * CSPLIT);
  float t = 0.0f;
  #pragma unroll
  for (int i = 0; i < CSPLIT / 4; ++i) {
    const float4 v = sp[i];
    t += v.x + v.y + v.z + v.w;
  }
  float nll = -pos_ws[r] + 2.0f + __logf(t);
  #pragma unroll
  for (int m = 1; m < 64; m <<= 1) nll += __shfl_xor(nll, m);
  __shared__ float red[4];
  const int lane = threadIdx.x & 63;
  const int wave = threadIdx.x >> 6;
  if (lane == 0) red[wave] = nll;
  __syncthreads();
  if (threadIdx.x == 0) partial[blockIdx.x] = red[0] + red[1] + red[2] + red[3];
}

// ---------------- Kernel 3b: final mean ----------------
__global__ __launch_bounds__(64) void final_kernel(const float* __restrict__ partial,
                                                   float* __restrict__ out) {
  const int lane = threadIdx.x;
  float v = (lane < 32) ? partial[lane] : 0.0f;
  #pragma unroll
  for (int m = 1; m < 64; m <<= 1) v += __shfl_xor(v, m);
  if (lane == 0) out[0] = v * (1.0f / (float)N2);
}

extern "C" void kernel_launch(void* const* d_in, const int* in_sizes, int n_in,
                              void* d_out, int out_size, void* d_ws, size_t ws_size,
                              hipStream_t stream) {
  const float* z1 = (const float*)d_in[0];
  const float* z2 = (const float*)d_in[1];
  float* out = (float*)d_out;

  char* ws = (char*)d_ws;
  short* zn = (short*)ws;                                   // 8192*256*2 = 4 MB
  float* sum_ws = (float*)(ws + (size_t)N2 * D * 2);        // 8192*16*4 = 512 KB
  float* pos_ws = sum_ws + (size_t)N2 * CSPLIT;             // 8192*4 = 32 KB
  float* partial = pos_ws + N2;                             // 32 floats

  hipLaunchKernelGGL(norm_kernel, dim3(N2 / 4), dim3(256), 0, stream, z1, z2, zn);
  hipLaunchKernelGGL(simlse_kernel, dim3(N2 / RPB, CSPLIT), dim3(256), 0, stream,
                     zn, sum_ws, pos_ws);
  hipLaunchKernelGGL(nll_kernel, dim3(N2 / 256), dim3(256), 0, stream, sum_ws, pos_ws, partial);
  hipLaunchKernelGGL(final_kernel, dim3(1), dim3(64), 0, stream, partial, out);
}